// Round 13
// baseline (960.314 us; speedup 1.0000x reference)
//
#include <hip/hip_runtime.h>
#include <stdint.h>

#define INV_T 10.0f
#define SHIFT_ 460.0f
#define MROWS 8192
#define DDIM 1024
#define CHUNK 1024

typedef __attribute__((ext_vector_type(8))) short bf16x8;
typedef __attribute__((ext_vector_type(4))) float f32x4;

__device__ __forceinline__ float bf2f(unsigned short u) {
  return __uint_as_float(((unsigned int)u) << 16);
}
__device__ __forceinline__ unsigned short f2bf(float f) {
  unsigned int u = __float_as_uint(f);
  return (unsigned short)((u + 0x7FFFu + ((u >> 16) & 1u)) >> 16);
}
__device__ __forceinline__ void gl2lds16(const unsigned short* g, unsigned short* l) {
  __builtin_amdgcn_global_load_lds((const __attribute__((address_space(1))) void*)g,
                                   (__attribute__((address_space(3))) void*)l, 16, 0, 0);
}

// ---------------- prep: fp32 -> bf16 cast + row sum-of-squares ----------------
__global__ void prep_kernel(const float* __restrict__ gen, const float* __restrict__ pos,
                            unsigned short* __restrict__ gen_h, unsigned short* __restrict__ pos_h,
                            float* __restrict__ gn2, float* __restrict__ pn2) {
  int b = blockIdx.x;
  const float* src; unsigned short* dst; float* n2; int row;
  if (b < MROWS) { src = gen; dst = gen_h; n2 = gn2; row = b; }
  else           { src = pos; dst = pos_h; n2 = pn2; row = b - MROWS; }
  int t = threadIdx.x;
  float4 v = ((const float4*)(src + (size_t)row * DDIM))[t];
  float ss = v.x * v.x + v.y * v.y + v.z * v.z + v.w * v.w;
  ushort4 o;
  o.x = f2bf(v.x); o.y = f2bf(v.y); o.z = f2bf(v.z); o.w = f2bf(v.w);
  ((ushort4*)(dst + (size_t)row * DDIM))[t] = o;
#pragma unroll
  for (int m = 1; m < 64; m <<= 1) ss += __shfl_xor(ss, m);
  __shared__ float red[4];
  if ((t & 63) == 0) red[t >> 6] = ss;
  __syncthreads();
  if (t == 0) n2[row] = red[0] + red[1] + red[2] + red[3];
}

// ---------------- transpose: fp32 [8192][1024] -> bf16 [1024][8192] ----------------
__global__ void transpose_kernel(const float* __restrict__ gen, const float* __restrict__ pos,
                                 unsigned short* __restrict__ genT, unsigned short* __restrict__ posT) {
  __shared__ float tile[64][65];
  int b = blockIdx.x;
  const float* src; unsigned short* dst;
  if (b < 2048) { src = gen; dst = genT; }
  else          { src = pos; dst = posT; b -= 2048; }
  int tj = b >> 4, td = b & 15;
  int t = threadIdx.x;
#pragma unroll
  for (int it = 0; it < 16; ++it) {
    int idx = it * 256 + t;
    int r = idx >> 6, c = idx & 63;
    tile[r][c] = src[(size_t)(tj * 64 + r) * DDIM + td * 64 + c];
  }
  __syncthreads();
#pragma unroll
  for (int it = 0; it < 16; ++it) {
    int idx = it * 256 + t;
    int d = idx >> 6, j = idx & 63;
    dst[(size_t)(td * 64 + d) * MROWS + tj * 64 + j] = f2bf(tile[j][d]);
  }
}

// ---------------- score GEMM, single chunk (verified 53 us form; round-7/8 gemm_bt<0>) ----------------
__launch_bounds__(256, 2)
__global__ void gemm_sc1(const unsigned short* __restrict__ Aq,
                         const unsigned short* __restrict__ Bpos,  // pos_h + j0*DDIM
                         const unsigned short* __restrict__ Bgen,  // gen_h + j0*DDIM
                         unsigned short* __restrict__ Pa, unsigned short* __restrict__ Pr,
                         int j0,
                         const float* __restrict__ gn2, const float* __restrict__ pn2,
                         float* __restrict__ lsumA, float* __restrict__ lsumR) {
  __shared__ __align__(16) unsigned short Al[128 * 64];
  __shared__ __align__(16) unsigned short Bl[128 * 64];

  const int orig = blockIdx.x + 64 * (blockIdx.y + 8 * blockIdx.z);
  const int wid = (orig & 7) * 128 + (orig >> 3);  // nwg=1024
  const int by = wid & 7;
  const int bx = (wid >> 3) & 63;
  const int z = wid >> 9;

  const unsigned short* B = z ? Bgen : Bpos;
  const float* kn2 = z ? gn2 : pn2;
  float* lsum = z ? lsumR : lsumA;
  unsigned short* Pout = z ? Pr : Pa;

  const int t = threadIdx.x;
  const int w = t >> 6, lane = t & 63, l15 = lane & 15, quad = lane >> 4;
  const int wm = w >> 1, wn = w & 1;
  const long m0 = (long)bx * 128;
  const long n0 = (long)by * 128;
  const int trow = t >> 3;
  const int tcol = (((t & 7) ^ (trow & 7)) * 8);

  f32x4 acc[4][4];
#pragma unroll
  for (int i = 0; i < 4; ++i)
#pragma unroll
    for (int j = 0; j < 4; ++j) acc[i][j] = (f32x4){0.f, 0.f, 0.f, 0.f};

  const unsigned short* Ab = Aq + (m0 + trow) * DDIM + tcol;
  const unsigned short* Bb = B + (n0 + trow) * DDIM + tcol;
  unsigned short* Alw = Al + t * 8;
  unsigned short* Blw = Bl + t * 8;
  const int ue = (quad ^ (l15 & 7)) * 8;

  for (int ks = 0; ks < DDIM / 64; ++ks) {
    const long ko = (long)ks * 64;
#pragma unroll
    for (int i = 0; i < 4; ++i) gl2lds16(Ab + (long)i * 32 * DDIM + ko, Alw + i * 2048);
#pragma unroll
    for (int i = 0; i < 4; ++i) gl2lds16(Bb + (long)i * 32 * DDIM + ko, Blw + i * 2048);
    __syncthreads();
#pragma unroll
    for (int kk = 0; kk < 2; ++kk) {
      const int uo = ue ^ (kk * 32);
      bf16x8 af[4], bfr[4];
#pragma unroll
      for (int mi = 0; mi < 4; ++mi)
        af[mi] = *(const bf16x8*)(Al + (wm * 64 + mi * 16 + l15) * 64 + uo);
#pragma unroll
      for (int ni = 0; ni < 4; ++ni)
        bfr[ni] = *(const bf16x8*)(Bl + (wn * 64 + ni * 16 + l15) * 64 + uo);
#pragma unroll
      for (int mi = 0; mi < 4; ++mi)
#pragma unroll
        for (int ni = 0; ni < 4; ++ni)
          acc[mi][ni] = __builtin_amdgcn_mfma_f32_16x16x32_bf16(af[mi], bfr[ni], acc[mi][ni], 0, 0, 0);
    }
    __syncthreads();
  }

#pragma unroll
  for (int mi = 0; mi < 4; ++mi) {
    float rs[4] = {0.f, 0.f, 0.f, 0.f};
#pragma unroll
    for (int ni = 0; ni < 4; ++ni) {
      int c = (int)n0 + wn * 64 + ni * 16 + l15;
      float kn = kn2[j0 + c];
#pragma unroll
      for (int reg = 0; reg < 4; ++reg) {
        long r = m0 + wm * 64 + mi * 16 + quad * 4 + reg;
        float v = acc[mi][ni][reg];
        float d2 = gn2[r] + kn - 2.0f * v;
        float p = __expf(SHIFT_ - INV_T * sqrtf(fmaxf(d2, 0.0f)));
        if (z && (int)r == (j0 + c)) p = 0.0f;
        rs[reg] += p;
        Pout[r * (long)CHUNK + c] = f2bf(p);
      }
    }
#pragma unroll
    for (int reg = 0; reg < 4; ++reg) {
      float v = rs[reg];
      v += __shfl_xor(v, 1); v += __shfl_xor(v, 2);
      v += __shfl_xor(v, 4); v += __shfl_xor(v, 8);
      if (l15 == 0) atomicAdd(&lsum[m0 + wm * 64 + mi * 16 + quad * 4 + reg], v);
    }
  }
}

// ---------------- shared K-segment macro (verified inner loop) ----------------
#define KSEG(Abase, Bbase, LDA_, LDB_)                                                     \
  {                                                                                        \
    const unsigned short* Ab_ = (Abase) + (m0 + trow) * (LDA_) + tcol;                     \
    const unsigned short* Bb_ = (Bbase) + (n0 + trow) * (LDB_) + tcol;                     \
    for (int ks = 0; ks < 16; ++ks) {                                                      \
      const long ko = (long)ks * 64;                                                       \
      _Pragma("unroll")                                                                    \
      for (int i = 0; i < 4; ++i) gl2lds16(Ab_ + (long)i * 32 * (LDA_) + ko, Alw + i * 2048); \
      _Pragma("unroll")                                                                    \
      for (int i = 0; i < 4; ++i) gl2lds16(Bb_ + (long)i * 32 * (LDB_) + ko, Blw + i * 2048); \
      __syncthreads();                                                                     \
      _Pragma("unroll")                                                                    \
      for (int kk = 0; kk < 2; ++kk) {                                                     \
        const int uo = ue ^ (kk * 32);                                                     \
        bf16x8 af[4], bfr[4];                                                              \
        _Pragma("unroll")                                                                  \
        for (int mi = 0; mi < 4; ++mi)                                                     \
          af[mi] = *(const bf16x8*)(Al + (wm * 64 + mi * 16 + l15) * 64 + uo);             \
        _Pragma("unroll")                                                                  \
        for (int ni = 0; ni < 4; ++ni)                                                     \
          bfr[ni] = *(const bf16x8*)(Bl + (wn * 64 + ni * 16 + l15) * 64 + uo);            \
        _Pragma("unroll")                                                                  \
        for (int mi = 0; mi < 4; ++mi)                                                     \
          _Pragma("unroll")                                                                \
          for (int ni = 0; ni < 4; ++ni)                                                   \
            acc[mi][ni] = __builtin_amdgcn_mfma_f32_16x16x32_bf16(af[mi], bfr[ni], acc[mi][ni], 0, 0, 0); \
      }                                                                                    \
      __syncthreads();                                                                     \
    }                                                                                      \
  }

// ---------------- PV GEMM, pair-fused (verified round-10/11 form), nseg=2 ----------------
__launch_bounds__(256, 2)
__global__ void gemm_pv2(const unsigned short* __restrict__ Pa0, const unsigned short* __restrict__ Pr0,
                         const unsigned short* __restrict__ Pa1, const unsigned short* __restrict__ Pr1,
                         const unsigned short* __restrict__ Va0, const unsigned short* __restrict__ Vr0,
                         const unsigned short* __restrict__ Va1, const unsigned short* __restrict__ Vr1,
                         unsigned short* __restrict__ OA, unsigned short* __restrict__ OR_,
                         int first) {
  __shared__ __align__(16) unsigned short Al[128 * 64];
  __shared__ __align__(16) unsigned short Bl[128 * 64];

  const int orig = blockIdx.x + 64 * (blockIdx.y + 8 * blockIdx.z);
  const int wid = (orig & 7) * 128 + (orig >> 3);  // nwg=1024
  const int by = wid & 7;
  const int bx = (wid >> 3) & 63;
  const int z = wid >> 9;

  const unsigned short* A0 = z ? Pr0 : Pa0;
  const unsigned short* B0 = z ? Vr0 : Va0;
  const unsigned short* A1 = z ? Pr1 : Pa1;
  const unsigned short* B1 = z ? Vr1 : Va1;

  const int t = threadIdx.x;
  const int w = t >> 6, lane = t & 63, l15 = lane & 15, quad = lane >> 4;
  const int wm = w >> 1, wn = w & 1;
  const long m0 = (long)bx * 128;
  const long n0 = (long)by * 128;
  const int trow = t >> 3;
  const int tcol = (((t & 7) ^ (trow & 7)) * 8);

  f32x4 acc[4][4];
#pragma unroll
  for (int i = 0; i < 4; ++i)
#pragma unroll
    for (int j = 0; j < 4; ++j) acc[i][j] = (f32x4){0.f, 0.f, 0.f, 0.f};

  unsigned short* Alw = Al + t * 8;
  unsigned short* Blw = Bl + t * 8;
  const int ue = (quad ^ (l15 & 7)) * 8;

  KSEG(A0, B0, CHUNK, MROWS);
  KSEG(A1, B1, CHUNK, MROWS);

  unsigned short* Oh = z ? OR_ : OA;
#pragma unroll
  for (int mi = 0; mi < 4; ++mi)
#pragma unroll
    for (int ni = 0; ni < 4; ++ni) {
      long c = n0 + wn * 64 + ni * 16 + l15;
#pragma unroll
      for (int reg = 0; reg < 4; ++reg) {
        long r = m0 + wm * 64 + mi * 16 + quad * 4 + reg;
        long off = r * DDIM + c;
        float v = acc[mi][ni][reg];
        Oh[off] = f2bf(first ? v : (bf2f(Oh[off]) + v));
      }
    }
}

// ---------------- MERGED dispatch: sc(cA0), sc(cA1) || pv(previous pair) ----------------
// 3072 blocks (12/CU queued). Role = wid%6 (block-uniform): 0,1 -> sc chunk A0 (z=rid);
// 2,3 -> sc chunk A1; 4,5 -> pv pair (z=rid-4). tile=wid/6 -> (bx,by). Each XCD's contiguous
// wid chunk (384 = 64 full role-cycles) holds all roles + a contiguous bx range (L2-friendly;
// the 4 sc roles of a tile share the A-panel). sc epilogue bursts overlap pv K-loops (m114).
__launch_bounds__(256, 2)
__global__ void gemm_mx(const unsigned short* __restrict__ Aq,
                        const unsigned short* __restrict__ Bpos,  // pos_h (base)
                        const unsigned short* __restrict__ Bgen,  // gen_h (base)
                        int j0A, int j0B,
                        unsigned short* __restrict__ PoA0, unsigned short* __restrict__ PoR0,
                        unsigned short* __restrict__ PoA1, unsigned short* __restrict__ PoR1,
                        const float* __restrict__ gn2, const float* __restrict__ pn2,
                        float* __restrict__ lsumA, float* __restrict__ lsumR,
                        const unsigned short* __restrict__ Pp0a, const unsigned short* __restrict__ Pp0r,
                        const unsigned short* __restrict__ Pp1a, const unsigned short* __restrict__ Pp1r,
                        const unsigned short* __restrict__ V0a, const unsigned short* __restrict__ V0r,
                        const unsigned short* __restrict__ V1a, const unsigned short* __restrict__ V1r,
                        unsigned short* __restrict__ OA, unsigned short* __restrict__ OR_,
                        int first) {
  __shared__ __align__(16) unsigned short Al[128 * 64];
  __shared__ __align__(16) unsigned short Bl[128 * 64];

  const int orig = blockIdx.x + 64 * (blockIdx.y + 8 * blockIdx.z);
  const int wid = (orig & 7) * 384 + (orig >> 3);   // nwg=3072, nwg/8=384 (384%6==0)
  const int rid = wid % 6;
  const int tile = wid / 6;                          // 0..511
  const int by = tile & 7;
  const int bx = tile >> 3;

  const int t = threadIdx.x;
  const int w = t >> 6, lane = t & 63, l15 = lane & 15, quad = lane >> 4;
  const int wm = w >> 1, wn = w & 1;
  const long m0 = (long)bx * 128;
  const long n0 = (long)by * 128;
  const int trow = t >> 3;
  const int tcol = (((t & 7) ^ (trow & 7)) * 8);

  unsigned short* Alw = Al + t * 8;
  unsigned short* Blw = Bl + t * 8;
  const int ue = (quad ^ (l15 & 7)) * 8;

  if (rid < 4) {
    // ---------------- sc role (verified body) ----------------
    const int z = rid & 1;
    const int j0 = (rid < 2) ? j0A : j0B;
    const unsigned short* Bs = z ? Bgen : Bpos;
    const float* kn2 = z ? gn2 : pn2;
    float* lsum = z ? lsumR : lsumA;
    unsigned short* Pout = (rid < 2) ? (z ? PoR0 : PoA0) : (z ? PoR1 : PoA1);

    f32x4 acc[4][4];
#pragma unroll
    for (int i = 0; i < 4; ++i)
#pragma unroll
      for (int j = 0; j < 4; ++j) acc[i][j] = (f32x4){0.f, 0.f, 0.f, 0.f};

    const unsigned short* Ab = Aq + (m0 + trow) * DDIM + tcol;
    const unsigned short* Bb = Bs + ((long)j0 + n0 + trow) * DDIM + tcol;

    for (int ks = 0; ks < DDIM / 64; ++ks) {
      const long ko = (long)ks * 64;
#pragma unroll
      for (int i = 0; i < 4; ++i) gl2lds16(Ab + (long)i * 32 * DDIM + ko, Alw + i * 2048);
#pragma unroll
      for (int i = 0; i < 4; ++i) gl2lds16(Bb + (long)i * 32 * DDIM + ko, Blw + i * 2048);
      __syncthreads();
#pragma unroll
      for (int kk = 0; kk < 2; ++kk) {
        const int uo = ue ^ (kk * 32);
        bf16x8 af[4], bfr[4];
#pragma unroll
        for (int mi = 0; mi < 4; ++mi)
          af[mi] = *(const bf16x8*)(Al + (wm * 64 + mi * 16 + l15) * 64 + uo);
#pragma unroll
        for (int ni = 0; ni < 4; ++ni)
          bfr[ni] = *(const bf16x8*)(Bl + (wn * 64 + ni * 16 + l15) * 64 + uo);
#pragma unroll
        for (int mi = 0; mi < 4; ++mi)
#pragma unroll
          for (int ni = 0; ni < 4; ++ni)
            acc[mi][ni] = __builtin_amdgcn_mfma_f32_16x16x32_bf16(af[mi], bfr[ni], acc[mi][ni], 0, 0, 0);
      }
      __syncthreads();
    }

#pragma unroll
    for (int mi = 0; mi < 4; ++mi) {
      float rs[4] = {0.f, 0.f, 0.f, 0.f};
#pragma unroll
      for (int ni = 0; ni < 4; ++ni) {
        int c = (int)n0 + wn * 64 + ni * 16 + l15;
        float kn = kn2[j0 + c];
#pragma unroll
        for (int reg = 0; reg < 4; ++reg) {
          long r = m0 + wm * 64 + mi * 16 + quad * 4 + reg;
          float v = acc[mi][ni][reg];
          float d2 = gn2[r] + kn - 2.0f * v;
          float p = __expf(SHIFT_ - INV_T * sqrtf(fmaxf(d2, 0.0f)));
          if (z && (int)r == (j0 + c)) p = 0.0f;
          rs[reg] += p;
          Pout[r * (long)CHUNK + c] = f2bf(p);
        }
      }
#pragma unroll
      for (int reg = 0; reg < 4; ++reg) {
        float v = rs[reg];
        v += __shfl_xor(v, 1); v += __shfl_xor(v, 2);
        v += __shfl_xor(v, 4); v += __shfl_xor(v, 8);
        if (l15 == 0) atomicAdd(&lsum[m0 + wm * 64 + mi * 16 + quad * 4 + reg], v);
      }
    }
  } else {
    // ---------------- pv role (verified pair body) ----------------
    const int z = rid - 4;
    const unsigned short* A0 = z ? Pp0r : Pp0a;
    const unsigned short* B0 = z ? V0r : V0a;
    const unsigned short* A1 = z ? Pp1r : Pp1a;
    const unsigned short* B1 = z ? V1r : V1a;

    f32x4 acc[4][4];
#pragma unroll
    for (int i = 0; i < 4; ++i)
#pragma unroll
      for (int j = 0; j < 4; ++j) acc[i][j] = (f32x4){0.f, 0.f, 0.f, 0.f};

    KSEG(A0, B0, CHUNK, MROWS);
    KSEG(A1, B1, CHUNK, MROWS);

    unsigned short* Oh = z ? OR_ : OA;
#pragma unroll
    for (int mi = 0; mi < 4; ++mi)
#pragma unroll
      for (int ni = 0; ni < 4; ++ni) {
        long c = n0 + wn * 64 + ni * 16 + l15;
#pragma unroll
        for (int reg = 0; reg < 4; ++reg) {
          long r = m0 + wm * 64 + mi * 16 + quad * 4 + reg;
          long off = r * DDIM + c;
          float v = acc[mi][ni][reg];
          Oh[off] = f2bf(first ? v : (bf2f(Oh[off]) + v));
        }
      }
  }
}
#undef KSEG

// ---------------- merged epilogue: all four stats in one pass; 4 atomics/block ----------------
__global__ void epi_kernel(const unsigned short* __restrict__ OA, const unsigned short* __restrict__ OR_,
                           const float* __restrict__ lsumA, const float* __restrict__ lsumR,
                           const float* __restrict__ genf, float* __restrict__ gs) {
  __shared__ float wsL[4], wsD[4], wsA[4], wsR[4];
  const int t = threadIdx.x;
  const int w = t >> 6;
  const int lane = t & 63;
  float accL = 0.f, accD = 0.f, accA = 0.f, accR = 0.f;

  for (int i = 0; i < 8; ++i) {
    const int row = blockIdx.x * 32 + w * 8 + i;
    const float invlA = 1.0f / lsumA[row];
    const float invlR = 1.0f / lsumR[row];
    float ssA = 0.f, ssR = 0.f, ssD = 0.f;
#pragma unroll
    for (int u = 0; u < 4; ++u) {
      const long off = (long)row * DDIM + u * 256 + lane * 4;
      float4 g = *(const float4*)(genf + off);
      ushort4 oa = *(const ushort4*)(OA + off);
      ushort4 orr = *(const ushort4*)(OR_ + off);
      float g4[4] = {g.x, g.y, g.z, g.w};
      float a4[4] = {bf2f(oa.x), bf2f(oa.y), bf2f(oa.z), bf2f(oa.w)};
      float r4[4] = {bf2f(orr.x), bf2f(orr.y), bf2f(orr.z), bf2f(orr.w)};
#pragma unroll
      for (int e = 0; e < 4; ++e) {
        float a_ = a4[e] * invlA - g4[e];
        float r_ = r4[e] * invlR - g4[e];
        float d_ = a_ - r_;
        ssA += a_ * a_; ssR += r_ * r_; ssD += d_ * d_;
      }
    }
#pragma unroll
    for (int m = 1; m < 64; m <<= 1) {
      ssA += __shfl_xor(ssA, m);
      ssR += __shfl_xor(ssR, m);
      ssD += __shfl_xor(ssD, m);
    }
    accA += sqrtf(ssA); accR += sqrtf(ssR); accD += sqrtf(ssD); accL += ssD;
  }
  if (lane == 0) { wsL[w] = accL; wsD[w] = accD; wsA[w] = accA; wsR[w] = accR; }
  __syncthreads();
  if (t == 0) {
    atomicAdd(&gs[0], wsL[0] + wsL[1] + wsL[2] + wsL[3]);
    atomicAdd(&gs[1], wsD[0] + wsD[1] + wsD[2] + wsD[3]);
    atomicAdd(&gs[2], wsA[0] + wsA[1] + wsA[2] + wsA[3]);
    atomicAdd(&gs[3], wsR[0] + wsR[1] + wsR[2] + wsR[3]);
  }
}

__global__ void finalize_kernel(const float* __restrict__ gs, float* __restrict__ out) {
  int t = threadIdx.x;
  if (t == 0) out[0] = gs[0] / (8192.0f * 1024.0f);
  if (t == 1) out[1] = gs[1] / 8192.0f;
  if (t == 2) out[2] = gs[2] / 8192.0f;
  if (t == 3) out[3] = gs[3] / 8192.0f;
}

extern "C" void kernel_launch(void* const* d_in, const int* in_sizes, int n_in,
                              void* d_out, int out_size, void* d_ws, size_t ws_size,
                              hipStream_t stream) {
  const float* gen = (const float*)d_in[0];
  const float* pos = (const float*)d_in[1];
  char* ws = (char*)d_ws;
  const size_t MB = (size_t)1 << 20;

  unsigned short* gen_h = (unsigned short*)(ws + 0 * MB);    // 16 MB
  unsigned short* pos_h = (unsigned short*)(ws + 16 * MB);   // 16 MB
  unsigned short* genT  = (unsigned short*)(ws + 32 * MB);   // 16 MB
  unsigned short* posT  = (unsigned short*)(ws + 48 * MB);   // 16 MB
  // P buffers: slot s (pair parity), chunk-in-pair ci, stream zz -> index k = s*4 + ci*2 + zz
  unsigned short* P[8];
  for (int k = 0; k < 8; ++k) P[k] = (unsigned short*)(ws + (64 + 16 * k) * MB);  // 64..192 MB
  unsigned short* OhA = (unsigned short*)(ws + 192 * MB);    // 16 MB
  unsigned short* OhR = (unsigned short*)(ws + 208 * MB);    // 16 MB
  float* gn2   = (float*)(ws + 224 * MB);
  float* pn2   = (float*)(ws + 224 * MB + 32768);
  float* lsumA = (float*)(ws + 224 * MB + 65536);
  float* lsumR = (float*)(ws + 224 * MB + 98304);
  float* gs    = (float*)(ws + 224 * MB + 131072);

  hipMemsetAsync(gs, 0, 4 * sizeof(float), stream);
  hipMemsetAsync(lsumA, 0, 2 * MROWS * sizeof(float), stream);  // lsumA + lsumR contiguous
  prep_kernel<<<dim3(16384), dim3(256), 0, stream>>>(gen, pos, gen_h, pos_h, gn2, pn2);
  transpose_kernel<<<dim3(4096), dim3(256), 0, stream>>>(gen, pos, genT, posT);

  // head: sc(c0), sc(c1) -> slot0
  gemm_sc1<<<dim3(64, 8, 2), dim3(256), 0, stream>>>(
      gen_h, pos_h, gen_h, P[0], P[1], 0, gn2, pn2, lsumA, lsumR);
  gemm_sc1<<<dim3(64, 8, 2), dim3(256), 0, stream>>>(
      gen_h, pos_h + (long)CHUNK * DDIM, gen_h + (long)CHUNK * DDIM,
      P[2], P[3], CHUNK, gn2, pn2, lsumA, lsumR);

  // merged phases: sc(2p+2, 2p+3) -> slot (p+1)&1 ; pv(pair p) from slot p&1
  for (int p = 0; p < 3; ++p) {
    const int sW = (p + 1) & 1, sR = p & 1;
    const int j0A = (2 * p + 2) * CHUNK, j0B = (2 * p + 3) * CHUNK;
    const long v0 = (long)(2 * p) * CHUNK, v1 = (long)(2 * p + 1) * CHUNK;
    gemm_mx<<<dim3(64, 8, 6), dim3(256), 0, stream>>>(
        gen_h, pos_h, gen_h, j0A, j0B,
        P[sW * 4 + 0], P[sW * 4 + 1], P[sW * 4 + 2], P[sW * 4 + 3],
        gn2, pn2, lsumA, lsumR,
        P[sR * 4 + 0], P[sR * 4 + 1], P[sR * 4 + 2], P[sR * 4 + 3],
        posT + v0, genT + v0, posT + v1, genT + v1,
        OhA, OhR, p == 0);
  }

  // tail: pv(pair 3) from slot 1
  {
    const long v0 = (long)6 * CHUNK, v1 = (long)7 * CHUNK;
    gemm_pv2<<<dim3(64, 8, 2), dim3(256), 0, stream>>>(
        P[4], P[5], P[6], P[7],
        posT + v0, genT + v0, posT + v1, genT + v1,
        OhA, OhR, 0);
  }

  epi_kernel<<<dim3(256), dim3(256), 0, stream>>>(OhA, OhR, lsumA, lsumR, gen, gs);
  finalize_kernel<<<dim3(1), dim3(64), 0, stream>>>(gs, (float*)d_out);
}

// Round 14
// 760.322 us; speedup vs baseline: 1.2630x; 1.2630x over previous
//
#include <hip/hip_runtime.h>
#include <stdint.h>

#define INV_T 10.0f
#define SHIFT_ 460.0f
#define MROWS 8192
#define DDIM 1024
#define CHUNK 1024

typedef __attribute__((ext_vector_type(8))) short bf16x8;
typedef __attribute__((ext_vector_type(4))) float f32x4;

__device__ __forceinline__ float bf2f(unsigned short u) {
  return __uint_as_float(((unsigned int)u) << 16);
}
__device__ __forceinline__ unsigned short f2bf(float f) {
  unsigned int u = __float_as_uint(f);
  return (unsigned short)((u + 0x7FFFu + ((u >> 16) & 1u)) >> 16);
}
__device__ __forceinline__ void gl2lds16(const unsigned short* g, unsigned short* l) {
  __builtin_amdgcn_global_load_lds((const __attribute__((address_space(1))) void*)g,
                                   (__attribute__((address_space(3))) void*)l, 16, 0, 0);
}

// ---------------- fused prep+transpose: ONE fp32 read -> bf16 row-major + bf16 transposed + n2 ----------------
// 4096 blocks (2048 gen + 2048 pos). Per block: 64x64 fp32 tile -> LDS; emit row-major bf16,
// transposed bf16, and per-row partial sum-of-squares (16 atomics/row over td blocks).
__global__ void prepT_kernel(const float* __restrict__ gen, const float* __restrict__ pos,
                             unsigned short* __restrict__ gen_h, unsigned short* __restrict__ pos_h,
                             unsigned short* __restrict__ genT, unsigned short* __restrict__ posT,
                             float* __restrict__ gn2, float* __restrict__ pn2) {
  __shared__ float tile[64][65];
  __shared__ float psum[64][4];
  int b = blockIdx.x;
  const float* src; unsigned short* dstT; unsigned short* dstH; float* n2;
  if (b < 2048) { src = gen; dstT = genT; dstH = gen_h; n2 = gn2; }
  else          { src = pos; dstT = posT; dstH = pos_h; n2 = pn2; b -= 2048; }
  int tj = b >> 4, td = b & 15;
  int t = threadIdx.x;
#pragma unroll
  for (int it = 0; it < 16; ++it) {
    int idx = it * 256 + t;
    int r = idx >> 6, c = idx & 63;
    tile[r][c] = src[(size_t)(tj * 64 + r) * DDIM + td * 64 + c];
  }
  __syncthreads();
  {
    int r4 = t >> 2, q = t & 3;  // 4 threads per row
    float s = 0.f;
#pragma unroll
    for (int i = 0; i < 16; ++i) { float v = tile[r4][q * 16 + i]; s += v * v; }
    psum[r4][q] = s;
  }
#pragma unroll
  for (int it = 0; it < 16; ++it) {
    int idx = it * 256 + t;
    int r = idx >> 6, c = idx & 63;
    dstH[(size_t)(tj * 64 + r) * DDIM + td * 64 + c] = f2bf(tile[r][c]);
  }
#pragma unroll
  for (int it = 0; it < 16; ++it) {
    int idx = it * 256 + t;
    int d = idx >> 6, j = idx & 63;
    dstT[(size_t)(td * 64 + d) * MROWS + tj * 64 + j] = f2bf(tile[j][d]);
  }
  __syncthreads();
  if (t < 64) {
    float s = psum[t][0] + psum[t][1] + psum[t][2] + psum[t][3];
    atomicAdd(&n2[tj * 64 + t], s);
  }
}

// ---------------- score GEMM, width-PAIR: two chunks, same role, one 2048-block dispatch ----------------
// Verified sc1 body; gy's top bit selects chunk-of-pair (block-uniform). 8 blocks/CU queued ->
// ramps amortized, epilogues overlap co-resident K-loops; A-panel shared by both chunks.
__launch_bounds__(256, 2)
__global__ void gemm_sc2(const unsigned short* __restrict__ Aq,
                         const unsigned short* __restrict__ Bpos,  // pos_h base
                         const unsigned short* __restrict__ Bgen,  // gen_h base
                         int j0lo, int j0hi,
                         unsigned short* __restrict__ PaLo, unsigned short* __restrict__ PrLo,
                         unsigned short* __restrict__ PaHi, unsigned short* __restrict__ PrHi,
                         const float* __restrict__ gn2, const float* __restrict__ pn2,
                         float* __restrict__ lsumA, float* __restrict__ lsumR) {
  __shared__ __align__(16) unsigned short Al[128 * 64];
  __shared__ __align__(16) unsigned short Bl[128 * 64];

  // chunked XCD swizzle (nwg=2048, %8==0), y-fastest
  const int orig = blockIdx.x + 64 * (blockIdx.y + 16 * blockIdx.z);
  const int wid = (orig & 7) * 256 + (orig >> 3);
  const int gy = wid & 15;
  const int bx = (wid >> 4) & 63;
  const int z = wid >> 10;
  const int hi = gy >> 3;
  const int by = gy & 7;

  const int j0 = hi ? j0hi : j0lo;
  const unsigned short* B = z ? Bgen : Bpos;
  const float* kn2 = z ? gn2 : pn2;
  float* lsum = z ? lsumR : lsumA;
  unsigned short* Pout = hi ? (z ? PrHi : PaHi) : (z ? PrLo : PaLo);

  const int t = threadIdx.x;
  const int w = t >> 6, lane = t & 63, l15 = lane & 15, quad = lane >> 4;
  const int wm = w >> 1, wn = w & 1;
  const long m0 = (long)bx * 128;
  const long n0 = (long)by * 128;
  const int trow = t >> 3;
  const int tcol = (((t & 7) ^ (trow & 7)) * 8);

  f32x4 acc[4][4];
#pragma unroll
  for (int i = 0; i < 4; ++i)
#pragma unroll
    for (int j = 0; j < 4; ++j) acc[i][j] = (f32x4){0.f, 0.f, 0.f, 0.f};

  const unsigned short* Ab = Aq + (m0 + trow) * DDIM + tcol;
  const unsigned short* Bb = B + ((long)j0 + n0 + trow) * DDIM + tcol;
  unsigned short* Alw = Al + t * 8;
  unsigned short* Blw = Bl + t * 8;
  const int ue = (quad ^ (l15 & 7)) * 8;

  for (int ks = 0; ks < DDIM / 64; ++ks) {
    const long ko = (long)ks * 64;
#pragma unroll
    for (int i = 0; i < 4; ++i) gl2lds16(Ab + (long)i * 32 * DDIM + ko, Alw + i * 2048);
#pragma unroll
    for (int i = 0; i < 4; ++i) gl2lds16(Bb + (long)i * 32 * DDIM + ko, Blw + i * 2048);
    __syncthreads();
#pragma unroll
    for (int kk = 0; kk < 2; ++kk) {
      const int uo = ue ^ (kk * 32);
      bf16x8 af[4], bfr[4];
#pragma unroll
      for (int mi = 0; mi < 4; ++mi)
        af[mi] = *(const bf16x8*)(Al + (wm * 64 + mi * 16 + l15) * 64 + uo);
#pragma unroll
      for (int ni = 0; ni < 4; ++ni)
        bfr[ni] = *(const bf16x8*)(Bl + (wn * 64 + ni * 16 + l15) * 64 + uo);
#pragma unroll
      for (int mi = 0; mi < 4; ++mi)
#pragma unroll
        for (int ni = 0; ni < 4; ++ni)
          acc[mi][ni] = __builtin_amdgcn_mfma_f32_16x16x32_bf16(af[mi], bfr[ni], acc[mi][ni], 0, 0, 0);
    }
    __syncthreads();
  }

#pragma unroll
  for (int mi = 0; mi < 4; ++mi) {
    float rs[4] = {0.f, 0.f, 0.f, 0.f};
#pragma unroll
    for (int ni = 0; ni < 4; ++ni) {
      int c = (int)n0 + wn * 64 + ni * 16 + l15;
      float kn = kn2[j0 + c];
#pragma unroll
      for (int reg = 0; reg < 4; ++reg) {
        long r = m0 + wm * 64 + mi * 16 + quad * 4 + reg;
        float v = acc[mi][ni][reg];
        float d2 = gn2[r] + kn - 2.0f * v;
        float p = __expf(SHIFT_ - INV_T * sqrtf(fmaxf(d2, 0.0f)));
        if (z && (int)r == (j0 + c)) p = 0.0f;
        rs[reg] += p;
        Pout[r * (long)CHUNK + c] = f2bf(p);
      }
    }
#pragma unroll
    for (int reg = 0; reg < 4; ++reg) {
      float v = rs[reg];
      v += __shfl_xor(v, 1); v += __shfl_xor(v, 2);
      v += __shfl_xor(v, 4); v += __shfl_xor(v, 8);
      if (l15 == 0) atomicAdd(&lsum[m0 + wm * 64 + mi * 16 + quad * 4 + reg], v);
    }
  }
}

// ---------------- PV GEMM, quad-fused (verified round-11 form): 64 K-steps/block ----------------
#define KSEG(Abase, Bbase, LDA_, LDB_)                                                     \
  {                                                                                        \
    const unsigned short* Ab_ = (Abase) + (m0 + trow) * (LDA_) + tcol;                     \
    const unsigned short* Bb_ = (Bbase) + (n0 + trow) * (LDB_) + tcol;                     \
    for (int ks = 0; ks < 16; ++ks) {                                                      \
      const long ko = (long)ks * 64;                                                       \
      _Pragma("unroll")                                                                    \
      for (int i = 0; i < 4; ++i) gl2lds16(Ab_ + (long)i * 32 * (LDA_) + ko, Alw + i * 2048); \
      _Pragma("unroll")                                                                    \
      for (int i = 0; i < 4; ++i) gl2lds16(Bb_ + (long)i * 32 * (LDB_) + ko, Blw + i * 2048); \
      __syncthreads();                                                                     \
      _Pragma("unroll")                                                                    \
      for (int kk = 0; kk < 2; ++kk) {                                                     \
        const int uo = ue ^ (kk * 32);                                                     \
        bf16x8 af[4], bfr[4];                                                              \
        _Pragma("unroll")                                                                  \
        for (int mi = 0; mi < 4; ++mi)                                                     \
          af[mi] = *(const bf16x8*)(Al + (wm * 64 + mi * 16 + l15) * 64 + uo);             \
        _Pragma("unroll")                                                                  \
        for (int ni = 0; ni < 4; ++ni)                                                     \
          bfr[ni] = *(const bf16x8*)(Bl + (wn * 64 + ni * 16 + l15) * 64 + uo);            \
        _Pragma("unroll")                                                                  \
        for (int mi = 0; mi < 4; ++mi)                                                     \
          _Pragma("unroll")                                                                \
          for (int ni = 0; ni < 4; ++ni)                                                   \
            acc[mi][ni] = __builtin_amdgcn_mfma_f32_16x16x32_bf16(af[mi], bfr[ni], acc[mi][ni], 0, 0, 0); \
      }                                                                                    \
      __syncthreads();                                                                     \
    }                                                                                      \
  }

__launch_bounds__(256, 2)
__global__ void gemm_pv(const unsigned short* __restrict__ Pa0, const unsigned short* __restrict__ Pr0,
                        const unsigned short* __restrict__ Pa1, const unsigned short* __restrict__ Pr1,
                        const unsigned short* __restrict__ Pa2, const unsigned short* __restrict__ Pr2,
                        const unsigned short* __restrict__ Pa3, const unsigned short* __restrict__ Pr3,
                        const unsigned short* __restrict__ Va0, const unsigned short* __restrict__ Vr0,
                        const unsigned short* __restrict__ Va1, const unsigned short* __restrict__ Vr1,
                        const unsigned short* __restrict__ Va2, const unsigned short* __restrict__ Vr2,
                        const unsigned short* __restrict__ Va3, const unsigned short* __restrict__ Vr3,
                        unsigned short* __restrict__ OA, unsigned short* __restrict__ OR_,
                        int first) {
  __shared__ __align__(16) unsigned short Al[128 * 64];
  __shared__ __align__(16) unsigned short Bl[128 * 64];

  const int orig = blockIdx.x + 64 * (blockIdx.y + 8 * blockIdx.z);
  const int wid = (orig & 7) * 128 + (orig >> 3);  // nwg=1024
  const int by = wid & 7;
  const int bx = (wid >> 3) & 63;
  const int z = wid >> 9;

  const unsigned short* A0 = z ? Pr0 : Pa0;
  const unsigned short* B0 = z ? Vr0 : Va0;
  const unsigned short* A1 = z ? Pr1 : Pa1;
  const unsigned short* B1 = z ? Vr1 : Va1;
  const unsigned short* A2 = z ? Pr2 : Pa2;
  const unsigned short* B2 = z ? Vr2 : Va2;
  const unsigned short* A3 = z ? Pr3 : Pa3;
  const unsigned short* B3 = z ? Vr3 : Va3;

  const int t = threadIdx.x;
  const int w = t >> 6, lane = t & 63, l15 = lane & 15, quad = lane >> 4;
  const int wm = w >> 1, wn = w & 1;
  const long m0 = (long)bx * 128;
  const long n0 = (long)by * 128;
  const int trow = t >> 3;
  const int tcol = (((t & 7) ^ (trow & 7)) * 8);

  f32x4 acc[4][4];
#pragma unroll
  for (int i = 0; i < 4; ++i)
#pragma unroll
    for (int j = 0; j < 4; ++j) acc[i][j] = (f32x4){0.f, 0.f, 0.f, 0.f};

  unsigned short* Alw = Al + t * 8;
  unsigned short* Blw = Bl + t * 8;
  const int ue = (quad ^ (l15 & 7)) * 8;

  KSEG(A0, B0, CHUNK, MROWS);
  KSEG(A1, B1, CHUNK, MROWS);
  KSEG(A2, B2, CHUNK, MROWS);
  KSEG(A3, B3, CHUNK, MROWS);

  unsigned short* Oh = z ? OR_ : OA;
#pragma unroll
  for (int mi = 0; mi < 4; ++mi)
#pragma unroll
    for (int ni = 0; ni < 4; ++ni) {
      long c = n0 + wn * 64 + ni * 16 + l15;
#pragma unroll
      for (int reg = 0; reg < 4; ++reg) {
        long r = m0 + wm * 64 + mi * 16 + quad * 4 + reg;
        long off = r * DDIM + c;
        float v = acc[mi][ni][reg];
        Oh[off] = f2bf(first ? v : (bf2f(Oh[off]) + v));
      }
    }
}
#undef KSEG

// ---------------- merged epilogue: all four stats in one pass; 4 atomics/block ----------------
__global__ void epi_kernel(const unsigned short* __restrict__ OA, const unsigned short* __restrict__ OR_,
                           const float* __restrict__ lsumA, const float* __restrict__ lsumR,
                           const float* __restrict__ genf, float* __restrict__ gs) {
  __shared__ float wsL[4], wsD[4], wsA[4], wsR[4];
  const int t = threadIdx.x;
  const int w = t >> 6;
  const int lane = t & 63;
  float accL = 0.f, accD = 0.f, accA = 0.f, accR = 0.f;

  for (int i = 0; i < 8; ++i) {
    const int row = blockIdx.x * 32 + w * 8 + i;
    const float invlA = 1.0f / lsumA[row];
    const float invlR = 1.0f / lsumR[row];
    float ssA = 0.f, ssR = 0.f, ssD = 0.f;
#pragma unroll
    for (int u = 0; u < 4; ++u) {
      const long off = (long)row * DDIM + u * 256 + lane * 4;
      float4 g = *(const float4*)(genf + off);
      ushort4 oa = *(const ushort4*)(OA + off);
      ushort4 orr = *(const ushort4*)(OR_ + off);
      float g4[4] = {g.x, g.y, g.z, g.w};
      float a4[4] = {bf2f(oa.x), bf2f(oa.y), bf2f(oa.z), bf2f(oa.w)};
      float r4[4] = {bf2f(orr.x), bf2f(orr.y), bf2f(orr.z), bf2f(orr.w)};
#pragma unroll
      for (int e = 0; e < 4; ++e) {
        float a_ = a4[e] * invlA - g4[e];
        float r_ = r4[e] * invlR - g4[e];
        float d_ = a_ - r_;
        ssA += a_ * a_; ssR += r_ * r_; ssD += d_ * d_;
      }
    }
#pragma unroll
    for (int m = 1; m < 64; m <<= 1) {
      ssA += __shfl_xor(ssA, m);
      ssR += __shfl_xor(ssR, m);
      ssD += __shfl_xor(ssD, m);
    }
    accA += sqrtf(ssA); accR += sqrtf(ssR); accD += sqrtf(ssD); accL += ssD;
  }
  if (lane == 0) { wsL[w] = accL; wsD[w] = accD; wsA[w] = accA; wsR[w] = accR; }
  __syncthreads();
  if (t == 0) {
    atomicAdd(&gs[0], wsL[0] + wsL[1] + wsL[2] + wsL[3]);
    atomicAdd(&gs[1], wsD[0] + wsD[1] + wsD[2] + wsD[3]);
    atomicAdd(&gs[2], wsA[0] + wsA[1] + wsA[2] + wsA[3]);
    atomicAdd(&gs[3], wsR[0] + wsR[1] + wsR[2] + wsR[3]);
  }
}

__global__ void finalize_kernel(const float* __restrict__ gs, float* __restrict__ out) {
  int t = threadIdx.x;
  if (t == 0) out[0] = gs[0] / (8192.0f * 1024.0f);
  if (t == 1) out[1] = gs[1] / 8192.0f;
  if (t == 2) out[2] = gs[2] / 8192.0f;
  if (t == 3) out[3] = gs[3] / 8192.0f;
}

extern "C" void kernel_launch(void* const* d_in, const int* in_sizes, int n_in,
                              void* d_out, int out_size, void* d_ws, size_t ws_size,
                              hipStream_t stream) {
  const float* gen = (const float*)d_in[0];
  const float* pos = (const float*)d_in[1];
  char* ws = (char*)d_ws;
  const size_t MB = (size_t)1 << 20;

  unsigned short* gen_h = (unsigned short*)(ws + 0 * MB);    // 16 MB
  unsigned short* pos_h = (unsigned short*)(ws + 16 * MB);   // 16 MB
  unsigned short* genT  = (unsigned short*)(ws + 32 * MB);   // 16 MB
  unsigned short* posT  = (unsigned short*)(ws + 48 * MB);   // 16 MB
  unsigned short* Pa[4] = {(unsigned short*)(ws + 64 * MB),  (unsigned short*)(ws + 96 * MB),
                           (unsigned short*)(ws + 128 * MB), (unsigned short*)(ws + 160 * MB)};
  unsigned short* Pr[4] = {(unsigned short*)(ws + 80 * MB),  (unsigned short*)(ws + 112 * MB),
                           (unsigned short*)(ws + 144 * MB), (unsigned short*)(ws + 176 * MB)};
  unsigned short* OhA = (unsigned short*)(ws + 192 * MB);    // 16 MB
  unsigned short* OhR = (unsigned short*)(ws + 208 * MB);    // 16 MB
  float* gn2   = (float*)(ws + 224 * MB);                    // 32 KB (atomics -> zeroed)
  float* pn2   = (float*)(ws + 224 * MB + 32768);            // 32 KB (atomics -> zeroed)
  float* lsumA = (float*)(ws + 224 * MB + 65536);            // 32 KB
  float* lsumR = (float*)(ws + 224 * MB + 98304);            // 32 KB
  float* gs    = (float*)(ws + 224 * MB + 131072);           // 16 B

  // zero gn2, pn2, lsumA, lsumR, gs in one contiguous memset
  hipMemsetAsync(gn2, 0, 131072 + 16, stream);
  prepT_kernel<<<dim3(4096), dim3(256), 0, stream>>>(gen, pos, gen_h, pos_h, genT, posT, gn2, pn2);

  for (int p = 0; p < 2; ++p) {
    const int c0 = 4 * p;
    gemm_sc2<<<dim3(64, 16, 2), dim3(256), 0, stream>>>(
        gen_h, pos_h, gen_h, c0 * CHUNK, (c0 + 1) * CHUNK,
        Pa[0], Pr[0], Pa[1], Pr[1], gn2, pn2, lsumA, lsumR);
    gemm_sc2<<<dim3(64, 16, 2), dim3(256), 0, stream>>>(
        gen_h, pos_h, gen_h, (c0 + 2) * CHUNK, (c0 + 3) * CHUNK,
        Pa[2], Pr[2], Pa[3], Pr[3], gn2, pn2, lsumA, lsumR);
    const long j0 = (long)c0 * CHUNK;
    gemm_pv<<<dim3(64, 8, 2), dim3(256), 0, stream>>>(
        Pa[0], Pr[0], Pa[1], Pr[1], Pa[2], Pr[2], Pa[3], Pr[3],
        posT + j0, genT + j0, posT + j0 + CHUNK, genT + j0 + CHUNK,
        posT + j0 + 2 * CHUNK, genT + j0 + 2 * CHUNK, posT + j0 + 3 * CHUNK, genT + j0 + 3 * CHUNK,
        OhA, OhR, p == 0);
  }

  epi_kernel<<<dim3(256), dim3(256), 0, stream>>>(OhA, OhR, lsumA, lsumR, gen, gs);
  finalize_kernel<<<dim3(1), dim3(64), 0, stream>>>(gs, (float*)d_out);
}